// Round 1
// baseline (96.460 us; speedup 1.0000x reference)
//
#include <hip/hip_runtime.h>

// Problem shape (fixed by setup_inputs): B=4, L=512, D=128
constexpr int L = 512;
constexpr int D = 128;

// out[b,i,d] = normalize_d( attsum(b,i)*input[b,i,d] + sum_j att[b,i,j]*rel[b,i,j,d] )
//
// The reference's GLOBAL l2-normalize of value_ cancels in the final per-row
// l2-normalize (the op is linear in value_ and the final normalize divides by
// the row norm, so any positive global scalar drops out; EPS guards inactive).
__global__ __launch_bounds__(256) void attemb_kernel(
    const float* __restrict__ att,   // [B,L,L]
    const float* __restrict__ inp,   // [B,L,D]
    const float* __restrict__ rel,   // [B,L,L,D]
    float* __restrict__ out)         // [B,L,D]
{
    const int bi = blockIdx.x;                       // b*L + i
    const float* attRow = att + (size_t)bi * L;
    const float* relRow = rel + (size_t)bi * (size_t)L * (size_t)D;
    const float* inRow  = inp + (size_t)bi * D;
    float*       outRow = out + (size_t)bi * D;

    const int tid  = threadIdx.x;    // 0..255
    const int jsub = tid >> 5;       // 0..7  (which j within a group of 8)
    const int dq   = tid & 31;       // 0..31 (which float4 of the 128-wide d)

    __shared__ float  s_att[L];
    __shared__ float  s_red[256];
    __shared__ float4 s_part[8][32];

    // Stage att row (512 f32 = 2 KiB) into LDS
    s_att[tid]       = attRow[tid];
    s_att[tid + 256] = attRow[tid + 256];
    __syncthreads();

    // Main accumulation: each thread owns 4 d-values for j = jsub, jsub+8, ...
    // Per wave: 64 lanes * 16B = 1024 contiguous bytes -> fully coalesced.
    float4 acc = make_float4(0.f, 0.f, 0.f, 0.f);
    #pragma unroll 4
    for (int j0 = 0; j0 < L; j0 += 8) {
        const int   j = j0 + jsub;
        const float a = s_att[j];                    // broadcast within 32 lanes
        const float4 v = *reinterpret_cast<const float4*>(
            relRow + (size_t)j * D + dq * 4);
        acc.x = fmaf(a, v.x, acc.x);
        acc.y = fmaf(a, v.y, acc.y);
        acc.z = fmaf(a, v.z, acc.z);
        acc.w = fmaf(a, v.w, acc.w);
    }

    // Stash partials; start attsum reduction
    s_part[jsub][dq] = acc;
    s_red[tid] = s_att[tid] + s_att[tid + 256];
    __syncthreads();
    for (int s = 128; s > 0; s >>= 1) {
        if (tid < s) s_red[tid] += s_red[tid + s];
        __syncthreads();
    }
    const float attsum = s_red[0];

    // First 32 threads: fold 8 jsub-partials, add attsum*input, row-normalize.
    if (tid < 32) {
        float4 tot = s_part[0][tid];
        #pragma unroll
        for (int g = 1; g < 8; ++g) {
            const float4 p = s_part[g][tid];
            tot.x += p.x; tot.y += p.y; tot.z += p.z; tot.w += p.w;
        }
        const float4 iv = *reinterpret_cast<const float4*>(inRow + tid * 4);
        tot.x = fmaf(attsum, iv.x, tot.x);
        tot.y = fmaf(attsum, iv.y, tot.y);
        tot.z = fmaf(attsum, iv.z, tot.z);
        tot.w = fmaf(attsum, iv.w, tot.w);

        float sq = tot.x * tot.x + tot.y * tot.y + tot.z * tot.z + tot.w * tot.w;
        #pragma unroll
        for (int m = 1; m < 32; m <<= 1) sq += __shfl_xor(sq, m);

        const float scale = rsqrtf(fmaxf(sq, 1e-12f));
        tot.x *= scale; tot.y *= scale; tot.z *= scale; tot.w *= scale;
        *reinterpret_cast<float4*>(outRow + tid * 4) = tot;
    }
}

extern "C" void kernel_launch(void* const* d_in, const int* in_sizes, int n_in,
                              void* d_out, int out_size, void* d_ws, size_t ws_size,
                              hipStream_t stream) {
    const float* att = (const float*)d_in[0];   // [B,L,L]
    const float* inp = (const float*)d_in[1];   // [B,L,D]
    const float* rel = (const float*)d_in[2];   // [B,L,L,D]
    float* out = (float*)d_out;                 // [B,L,D]

    const int B = in_sizes[1] / (L * D);        // = 4
    const int nBlocks = B * L;                  // 2048
    attemb_kernel<<<nBlocks, 256, 0, stream>>>(att, inp, rel, out);
}

// Round 3
// 84.985 us; speedup vs baseline: 1.1350x; 1.1350x over previous
//
#include <hip/hip_runtime.h>

// Problem shape (fixed by setup_inputs): B=4, L=512, D=128
constexpr int L = 512;
constexpr int D = 128;

typedef float f32x4 __attribute__((ext_vector_type(4)));

// out[b,i,d] = normalize_d( attsum(b,i)*input[b,i,d] + sum_j att[b,i,j]*rel[b,i,j,d] )
//
// The reference's GLOBAL l2-normalize of value_ cancels in the final per-row
// l2-normalize (the op is linear in value_, and the final normalize divides
// by the row norm, so any positive global scalar drops out; EPS guards are
// never active for this data). So: single pass over rel, no global-norm pass.
__global__ __launch_bounds__(256) void attemb_kernel(
    const float* __restrict__ att,   // [B,L,L]
    const float* __restrict__ inp,   // [B,L,D]
    const float* __restrict__ rel,   // [B,L,L,D]
    float* __restrict__ out)         // [B,L,D]
{
    const int bi = blockIdx.x;                       // b*L + i
    const float* attRow = att + (size_t)bi * L;
    const float* relRow = rel + (size_t)bi * (size_t)L * (size_t)D;
    const float* inRow  = inp + (size_t)bi * D;
    float*       outRow = out + (size_t)bi * D;

    const int tid  = threadIdx.x;    // 0..255
    const int jsub = tid >> 5;       // 0..7
    const int dq   = tid & 31;       // 0..31 (which float4 of the 128-wide d)

    __shared__ float s_att[L];
    __shared__ float s_wsum[4];
    __shared__ f32x4 s_part[8][32];

    // Stage att row (512 f32) into LDS; fold attsum via per-wave shuffle.
    const float a0 = attRow[tid];
    const float a1 = attRow[tid + 256];
    s_att[tid]       = a0;
    s_att[tid + 256] = a1;
    float asum = a0 + a1;
    #pragma unroll
    for (int m = 1; m < 64; m <<= 1) asum += __shfl_xor(asum, m);
    if ((tid & 63) == 0) s_wsum[tid >> 6] = asum;
    __syncthreads();

    // Main accumulation: 32 steps, 2 independent float4 nt-loads per step
    // (j and j+8). Per wave per step: 2 x 1024B contiguous segments.
    f32x4 acc0 = (f32x4)(0.f);
    f32x4 acc1 = (f32x4)(0.f);
    #pragma unroll 4
    for (int j0 = 0; j0 < L; j0 += 16) {
        const int j = j0 + jsub;
        const float aLo = s_att[j];
        const float aHi = s_att[j + 8];
        const f32x4* p0 = reinterpret_cast<const f32x4*>(
            relRow + (size_t)j * D + dq * 4);
        const f32x4* p1 = reinterpret_cast<const f32x4*>(
            relRow + (size_t)(j + 8) * D + dq * 4);
        const f32x4 v0 = __builtin_nontemporal_load(p0);
        const f32x4 v1 = __builtin_nontemporal_load(p1);
        acc0 += aLo * v0;
        acc1 += aHi * v1;
    }
    acc0 += acc1;

    s_part[jsub][dq] = acc0;
    __syncthreads();

    // First 32 threads: fold 8 jsub-partials, add attsum*input, row-normalize.
    if (tid < 32) {
        const float attsum = s_wsum[0] + s_wsum[1] + s_wsum[2] + s_wsum[3];
        f32x4 tot = s_part[0][tid];
        #pragma unroll
        for (int g = 1; g < 8; ++g) tot += s_part[g][tid];

        const f32x4 iv = *reinterpret_cast<const f32x4*>(inRow + tid * 4);
        tot += attsum * iv;

        float sq = tot.x * tot.x + tot.y * tot.y + tot.z * tot.z + tot.w * tot.w;
        #pragma unroll
        for (int m = 1; m < 32; m <<= 1) sq += __shfl_xor(sq, m);

        const float scale = rsqrtf(fmaxf(sq, 1e-12f));
        tot *= scale;
        *reinterpret_cast<f32x4*>(outRow + tid * 4) = tot;
    }
}

extern "C" void kernel_launch(void* const* d_in, const int* in_sizes, int n_in,
                              void* d_out, int out_size, void* d_ws, size_t ws_size,
                              hipStream_t stream) {
    const float* att = (const float*)d_in[0];   // [B,L,L]
    const float* inp = (const float*)d_in[1];   // [B,L,D]
    const float* rel = (const float*)d_in[2];   // [B,L,L,D]
    float* out = (float*)d_out;                 // [B,L,D]

    const int B = in_sizes[1] / (L * D);        // = 4
    const int nBlocks = B * L;                  // 2048
    attemb_kernel<<<nBlocks, 256, 0, stream>>>(att, inp, rel, out);
}